// Round 1
// 346.917 us; speedup vs baseline: 1.1590x; 1.1590x over previous
//
#include <hip/hip_runtime.h>
#include <math.h>

// Problem constants
#define BB 16
#define CE 1024
#define TT 2048
#define KK 4096
#define CC 64

// d_out offsets (floats): codes (B,T) | quantized (B,CE,T) | cb_loss | commit_loss
//                         | x_proj (B,CC,T) | quantized_proj (B,CC,T)
#define O_CODES 0
#define O_QUANT 32768
#define O_CBL   33587200
#define O_CML   33587201
#define O_XPROJ 33587202
#define O_QPROJ 35684354

// workspace offsets (floats)
#define W_WINF  0         // W_in fp16 frags hi|lo: half8[2][4][32][64] (1 MB)
#define W_WOUTF 262144    // W_out fp16 frags hi|lo: half8[2][64][2][64] (256 KB)
#define W_CBSQ  327680    // sum(cb_n^2) per k [4096]
#define W_LOSS  659456    // float accumulator (+pad)
#define W_BF    659520    // cb frags fp16 hi|lo, 262144 floats (1 MB)

typedef __attribute__((ext_vector_type(8))) _Float16 half8;
typedef __attribute__((ext_vector_type(4))) float f32x4;

// ---------------------------------------------------------------------------
// Kernel 1: weight-norm W_in/W_out -> fp16 hi/lo MFMA A-frags;
// codebook -> cbsq + fp16 hi/lo B-frags.  (unchanged, verified)
// Frag convention (16x16x32 f16):
//   A[m][k]: lane = ((k>>3)&3)*16 + (m&15), j = k&7
//   B[k][n]: lane = ((k>>3)&3)*16 + (n&15), j = k&7
//   D: row(m) = (lane>>4)*4 + reg, col(n) = lane&15
// ---------------------------------------------------------------------------
__global__ __launch_bounds__(64) void prep_kernel(
    const float* __restrict__ v_in, const float* __restrict__ g_in,
    const float* __restrict__ v_out, const float* __restrict__ g_out,
    const float* __restrict__ cb, float* __restrict__ ws) {
  int bid = blockIdx.x, tid = threadIdx.x;
  if (bid == 0 && tid == 0) ws[W_LOSS] = 0.f;
  if (bid < 64) {
    int o = bid;
    float s = 0.f;
    for (int i = tid; i < CE; i += 64) { float v = v_in[o * CE + i]; s += v * v; }
    for (int off = 32; off; off >>= 1) s += __shfl_down(s, off);
    s = __shfl(s, 0);
    float norm = sqrtf(s);
    float g = g_in[o];
    _Float16* wf = (_Float16*)(ws + W_WINF);
    int ot = o >> 4, m = o & 15;
    for (int i = tid; i < CE; i += 64) {
      float w = (g * v_in[o * CE + i]) / norm;
      _Float16 hi = (_Float16)w;
      _Float16 lo = (_Float16)(w - (float)hi);
      int ks = i >> 5, q = (i >> 3) & 3, j = i & 7;
      int lane = q * 16 + m;
      int base = ((ot * 32 + ks) * 64 + lane) * 8 + j;
      wf[base] = hi;
      wf[65536 + base] = lo;
    }
  } else if (bid < 64 + CE) {
    int o = bid - 64;
    int c = tid;
    float v = v_out[o * CC + c];
    float s = v * v;
    for (int off = 32; off; off >>= 1) s += __shfl_down(s, off);
    s = __shfl(s, 0);
    float w = (g_out[o] * v) / sqrtf(s);
    _Float16 hi = (_Float16)w;
    _Float16 lo = (_Float16)(w - (float)hi);
    _Float16* wf = (_Float16*)(ws + W_WOUTF);
    int ot = o >> 4, m = o & 15;
    int ks = c >> 5, q = (c >> 3) & 3, j = c & 7;
    int lane = q * 16 + m;
    int base = ((ot * 2 + ks) * 64 + lane) * 8 + j;
    wf[base] = hi;
    wf[131072 / 2 + base] = lo;
  } else {
    int k = bid - 64 - CE;
    int c = tid;
    float v = cb[k * CC + c];
    float s = v * v;
    for (int off = 32; off; off >>= 1) s += __shfl_down(s, off);
    s = __shfl(s, 0);
    float n = fmaxf(sqrtf(s), 1e-12f);
    float cn = v / n;
    float s2 = cn * cn;
    for (int off = 32; off; off >>= 1) s2 += __shfl_down(s2, off);
    if (tid == 0) ws[W_CBSQ + k] = s2;
    _Float16 hi = (_Float16)cn;
    _Float16 lo = (_Float16)(cn - (float)hi);
    _Float16* bfh = (_Float16*)(ws + W_BF);
    int ntile = k >> 4, ki = c >> 5;
    int lane = ((c >> 3) & 3) * 16 + (k & 15);
    int j = c & 7;
    int idx = (((ntile * 2 + ki) * 64 + lane) << 3) + j;
    bfh[idx] = hi;
    bfh[262144 + idx] = lo;
  }
}

// ---------------------------------------------------------------------------
// Kernel 2 (FUSED): proj -> dist/argmin -> merge -> gather -> W_out GEMM.
// grid 512 = b*32 + t-chunk(64); block 256 = 4 waves.
// Phase 1: wave w computes x_proj for its 16 t (all 64 c) -> LDS + out.
// Phase 2: wave w = k-split, covers ALL 64 t of the block, codes
//          [w*1024, (w+1)*1024); partial argmin -> LDS; merged by tid<64.
// Phase 3: wave w gathers codebook rows for its 16 t, losses, W_out GEMM.
// All GEMM inner loops use depth-1 double-buffer prefetch.
// ---------------------------------------------------------------------------
__global__ __launch_bounds__(256, 2) void fused_kernel(
    const float* __restrict__ x, const float* __restrict__ cb,
    const float* __restrict__ ws, float* __restrict__ out,
    float* loss_acc) {
  __shared__ float xls[64][68];   // [t_local][c] raw x_proj (padded rows)
  __shared__ float nrmS[64];
  __shared__ float pbS[4][64];
  __shared__ int   piS[4][64];
  __shared__ int   codeS[64];

  int tid = threadIdx.x;
  int w = tid >> 6, l = tid & 63;
  int n = l & 15, q = l >> 4;
  int blk = blockIdx.x;
  int b = blk >> 5, t0 = (blk & 31) * 64;

  const half8* wfin = (const half8*)(ws + W_WINF);
  const half8* wfo  = (const half8*)(ws + W_WOUTF);
  const half8* bfr  = (const half8*)(ws + W_BF);
  const float* cbsq = ws + W_CBSQ;

  // ---- Phase 1: x_proj for t = t0 + w*16 + n ----
  {
    int t = t0 + w * 16 + n;
    const float* xp = x + (size_t)b * CE * TT + t;
    f32x4 acc[4];
#pragma unroll
    for (int ot = 0; ot < 4; ++ot) acc[ot] = (f32x4){0.f, 0.f, 0.f, 0.f};

    float v[2][8];
    half8 wh[2][4], wl[2][4];
    // prologue: ks = 0
#pragma unroll
    for (int j = 0; j < 8; ++j) v[0][j] = xp[(size_t)(q * 8 + j) * TT];
#pragma unroll
    for (int ot = 0; ot < 4; ++ot) {
      wh[0][ot] = wfin[(ot * 32 + 0) * 64 + l];
      wl[0][ot] = wfin[8192 + (ot * 32 + 0) * 64 + l];
    }
#pragma unroll 2
    for (int ks = 0; ks < 32; ++ks) {
      int cur = ks & 1;
      if (ks < 31) {
        int kb = (ks + 1) * 32 + q * 8;
#pragma unroll
        for (int j = 0; j < 8; ++j) v[cur ^ 1][j] = xp[(size_t)(kb + j) * TT];
#pragma unroll
        for (int ot = 0; ot < 4; ++ot) {
          wh[cur ^ 1][ot] = wfin[(ot * 32 + ks + 1) * 64 + l];
          wl[cur ^ 1][ot] = wfin[8192 + (ot * 32 + ks + 1) * 64 + l];
        }
      }
      half8 xh, xl;
#pragma unroll
      for (int j = 0; j < 8; ++j) xh[j] = (_Float16)v[cur][j];
#pragma unroll
      for (int j = 0; j < 8; ++j) xl[j] = (_Float16)(v[cur][j] - (float)xh[j]);
#pragma unroll
      for (int ot = 0; ot < 4; ++ot)
        acc[ot] = __builtin_amdgcn_mfma_f32_16x16x32_f16(wh[cur][ot], xh, acc[ot], 0, 0, 0);
#pragma unroll
      for (int ot = 0; ot < 4; ++ot)
        acc[ot] = __builtin_amdgcn_mfma_f32_16x16x32_f16(wh[cur][ot], xl, acc[ot], 0, 0, 0);
#pragma unroll
      for (int ot = 0; ot < 4; ++ot)
        acc[ot] = __builtin_amdgcn_mfma_f32_16x16x32_f16(wl[cur][ot], xh, acc[ot], 0, 0, 0);
    }

    float s = 0.f;
    int tl = w * 16 + n;
#pragma unroll
    for (int ot = 0; ot < 4; ++ot) {
#pragma unroll
      for (int r = 0; r < 4; ++r) {
        float vv = acc[ot][r];
        out[O_XPROJ + (size_t)(b * CC + ot * 16 + q * 4 + r) * TT + t] = vv;
        s = fmaf(vv, vv, s);
      }
      *(f32x4*)&xls[tl][ot * 16 + q * 4] = acc[ot];
    }
    s += __shfl_xor(s, 16);
    s += __shfl_xor(s, 32);
    if (l < 16) nrmS[tl] = fmaxf(sqrtf(s), 1e-12f);
  }
  __syncthreads();

  // ---- Phase 2: dist/argmin; wave w handles codes [w*1024, (w+1)*1024) ----
  {
    half8 Ahi[4][2], Alo[4][2];
#pragma unroll
    for (int bd = 0; bd < 4; ++bd) {
      int tl = bd * 16 + n;
      float nv = nrmS[tl];
#pragma unroll
      for (int ki = 0; ki < 2; ++ki) {
#pragma unroll
        for (int j = 0; j < 8; ++j) {
          float vv = xls[tl][ki * 32 + q * 8 + j] / nv;
          _Float16 h = (_Float16)vv;
          Ahi[bd][ki][j] = h;
          Alo[bd][ki][j] = (_Float16)(vv - (float)h);
        }
      }
    }

    float best[4][4];
    int bidx[4][4];
#pragma unroll
    for (int bd = 0; bd < 4; ++bd)
#pragma unroll
      for (int r = 0; r < 4; ++r) { best[bd][r] = 3.4e38f; bidx[bd][r] = 0; }

    half8 Bh0[2], Bh1[2], Bl0[2], Bl1[2];
    float cq[2];
    {
      int nt = w * 64;
      Bh0[0] = bfr[(nt * 2 + 0) * 64 + l];
      Bh1[0] = bfr[(nt * 2 + 1) * 64 + l];
      Bl0[0] = bfr[32768 + (nt * 2 + 0) * 64 + l];
      Bl1[0] = bfr[32768 + (nt * 2 + 1) * 64 + l];
      cq[0] = cbsq[nt * 16 + n];
    }
#pragma unroll 2
    for (int it = 0; it < 64; ++it) {
      int cur = it & 1;
      int nt = w * 64 + it;
      if (it < 63) {
        int nt2 = nt + 1;
        Bh0[cur ^ 1] = bfr[(nt2 * 2 + 0) * 64 + l];
        Bh1[cur ^ 1] = bfr[(nt2 * 2 + 1) * 64 + l];
        Bl0[cur ^ 1] = bfr[32768 + (nt2 * 2 + 0) * 64 + l];
        Bl1[cur ^ 1] = bfr[32768 + (nt2 * 2 + 1) * 64 + l];
        cq[cur ^ 1] = cbsq[nt2 * 16 + n];
      }
      f32x4 acc[4];
#pragma unroll
      for (int bd = 0; bd < 4; ++bd) acc[bd] = (f32x4){0.f, 0.f, 0.f, 0.f};
#pragma unroll
      for (int bd = 0; bd < 4; ++bd)
        acc[bd] = __builtin_amdgcn_mfma_f32_16x16x32_f16(Ahi[bd][0], Bh0[cur], acc[bd], 0, 0, 0);
#pragma unroll
      for (int bd = 0; bd < 4; ++bd)
        acc[bd] = __builtin_amdgcn_mfma_f32_16x16x32_f16(Ahi[bd][1], Bh1[cur], acc[bd], 0, 0, 0);
#pragma unroll
      for (int bd = 0; bd < 4; ++bd)
        acc[bd] = __builtin_amdgcn_mfma_f32_16x16x32_f16(Alo[bd][0], Bh0[cur], acc[bd], 0, 0, 0);
#pragma unroll
      for (int bd = 0; bd < 4; ++bd)
        acc[bd] = __builtin_amdgcn_mfma_f32_16x16x32_f16(Alo[bd][1], Bh1[cur], acc[bd], 0, 0, 0);
#pragma unroll
      for (int bd = 0; bd < 4; ++bd)
        acc[bd] = __builtin_amdgcn_mfma_f32_16x16x32_f16(Ahi[bd][0], Bl0[cur], acc[bd], 0, 0, 0);
#pragma unroll
      for (int bd = 0; bd < 4; ++bd)
        acc[bd] = __builtin_amdgcn_mfma_f32_16x16x32_f16(Ahi[bd][1], Bl1[cur], acc[bd], 0, 0, 0);

      int kl = nt * 16 + n;
#pragma unroll
      for (int bd = 0; bd < 4; ++bd)
#pragma unroll
        for (int r = 0; r < 4; ++r) {
          float sc = fmaf(-2.f, acc[bd][r], cq[cur]);
          if (sc < best[bd][r]) { best[bd][r] = sc; bidx[bd][r] = kl; }
        }
    }

#pragma unroll
    for (int st = 1; st < 16; st <<= 1) {
#pragma unroll
      for (int bd = 0; bd < 4; ++bd)
#pragma unroll
        for (int r = 0; r < 4; ++r) {
          float os = __shfl_xor(best[bd][r], st);
          int oi = __shfl_xor(bidx[bd][r], st);
          if (os < best[bd][r] || (os == best[bd][r] && oi < bidx[bd][r])) {
            best[bd][r] = os;
            bidx[bd][r] = oi;
          }
        }
    }
    if (n == 0) {
#pragma unroll
      for (int bd = 0; bd < 4; ++bd)
#pragma unroll
        for (int r = 0; r < 4; ++r) {
          int tl = bd * 16 + q * 4 + r;
          pbS[w][tl] = best[bd][r];
          piS[w][tl] = bidx[bd][r];
        }
    }
  }
  __syncthreads();

  // ---- merge 4 k-splits (lowest index wins ties) ----
  if (tid < 64) {
    float bs = pbS[0][tid];
    int bi = piS[0][tid];
#pragma unroll
    for (int s = 1; s < 4; ++s) {
      float s2 = pbS[s][tid];
      int i2 = piS[s][tid];
      if (s2 < bs || (s2 == bs && i2 < bi)) { bs = s2; bi = i2; }
    }
    codeS[tid] = bi;
    out[O_CODES + b * TT + t0 + tid] = (float)bi;
  }
  __syncthreads();

  // ---- Phase 3: gather + q_proj + loss + W_out GEMM ----
  {
    int t = t0 + w * 16 + n;
    int tl = w * 16 + n;
    int code = codeS[tl];
    const float* cbr = cb + (size_t)code * CC;
    float qv[2][8];
#pragma unroll
    for (int ks = 0; ks < 2; ++ks) {
      float4 a = *(const float4*)&cbr[ks * 32 + q * 8];
      float4 c4 = *(const float4*)&cbr[ks * 32 + q * 8 + 4];
      qv[ks][0] = a.x; qv[ks][1] = a.y; qv[ks][2] = a.z; qv[ks][3] = a.w;
      qv[ks][4] = c4.x; qv[ks][5] = c4.y; qv[ks][6] = c4.z; qv[ks][7] = c4.w;
    }

    float ls = 0.f;
#pragma unroll
    for (int ks = 0; ks < 2; ++ks)
#pragma unroll
      for (int j = 0; j < 8; ++j) {
        int c = ks * 32 + q * 8 + j;
        float qq = qv[ks][j];
        out[O_QPROJ + (size_t)(b * CC + c) * TT + t] = qq;
        float d = xls[tl][c] - qq;
        ls = fmaf(d, d, ls);
      }
    for (int off = 32; off; off >>= 1) ls += __shfl_down(ls, off);
    if (l == 0) atomicAdd(loss_acc, ls);

    half8 qh[2], ql[2];
#pragma unroll
    for (int ks = 0; ks < 2; ++ks)
#pragma unroll
      for (int j = 0; j < 8; ++j) {
        qh[ks][j] = (_Float16)qv[ks][j];
        ql[ks][j] = (_Float16)(qv[ks][j] - (float)qh[ks][j]);
      }

    // W_out GEMM: 64 o-tiles, prefetch next tile's frags while computing
    half8 wc[2][4];  // [buf] x {wh0, wh1, wl0, wl1}
    wc[0][0] = wfo[0 * 64 + l];
    wc[0][1] = wfo[1 * 64 + l];
    wc[0][2] = wfo[8192 + 0 * 64 + l];
    wc[0][3] = wfo[8192 + 1 * 64 + l];
#pragma unroll 2
    for (int ot = 0; ot < 64; ++ot) {
      int cur = ot & 1;
      if (ot < 63) {
        int o2 = ot + 1;
        wc[cur ^ 1][0] = wfo[(o2 * 2 + 0) * 64 + l];
        wc[cur ^ 1][1] = wfo[(o2 * 2 + 1) * 64 + l];
        wc[cur ^ 1][2] = wfo[8192 + (o2 * 2 + 0) * 64 + l];
        wc[cur ^ 1][3] = wfo[8192 + (o2 * 2 + 1) * 64 + l];
      }
      f32x4 acc = (f32x4){0.f, 0.f, 0.f, 0.f};
      acc = __builtin_amdgcn_mfma_f32_16x16x32_f16(wc[cur][0], qh[0], acc, 0, 0, 0);
      acc = __builtin_amdgcn_mfma_f32_16x16x32_f16(wc[cur][1], qh[1], acc, 0, 0, 0);
      acc = __builtin_amdgcn_mfma_f32_16x16x32_f16(wc[cur][0], ql[0], acc, 0, 0, 0);
      acc = __builtin_amdgcn_mfma_f32_16x16x32_f16(wc[cur][1], ql[1], acc, 0, 0, 0);
      acc = __builtin_amdgcn_mfma_f32_16x16x32_f16(wc[cur][2], qh[0], acc, 0, 0, 0);
      acc = __builtin_amdgcn_mfma_f32_16x16x32_f16(wc[cur][3], qh[1], acc, 0, 0, 0);
#pragma unroll
      for (int r = 0; r < 4; ++r)
        out[O_QUANT + (size_t)(b * CE + ot * 16 + q * 4 + r) * TT + t] = acc[r];
    }
  }
}

// ---------------------------------------------------------------------------
// Kernel 3: finalize losses
// ---------------------------------------------------------------------------
__global__ void finalize_kernel(const float* __restrict__ ws, float* __restrict__ out) {
  if (threadIdx.x == 0 && blockIdx.x == 0) {
    float l = ws[W_LOSS] / 2097152.f;  // B*CC*T
    out[O_CBL] = l;
    out[O_CML] = l;
  }
}

extern "C" void kernel_launch(void* const* d_in, const int* in_sizes, int n_in,
                              void* d_out, int out_size, void* d_ws, size_t ws_size,
                              hipStream_t stream) {
  const float* x     = (const float*)d_in[0];
  const float* v_in  = (const float*)d_in[1];
  const float* g_in  = (const float*)d_in[2];
  const float* v_out = (const float*)d_in[3];
  const float* g_out = (const float*)d_in[4];
  const float* cb    = (const float*)d_in[5];
  float* out = (float*)d_out;
  float* ws  = (float*)d_ws;

  prep_kernel<<<64 + 1024 + 4096, 64, 0, stream>>>(v_in, g_in, v_out, g_out, cb, ws);
  fused_kernel<<<512, 256, 0, stream>>>(x, cb, ws, out, ws + W_LOSS);
  finalize_kernel<<<1, 64, 0, stream>>>(ws, out);
}